// Round 7
// baseline (107.828 us; speedup 1.0000x reference)
//
#include <hip/hip_runtime.h>
#include <stdint.h>
#include <stddef.h>

// MambaMesh random-walk + gather-recenter.  R7: in-kernel LDS/global choice.
// PRNG (bit-exact vs JAX partitionable Threefry, verified R1-R6, absmax 0.0):
//   split(key,n)[j]        = threefry2x32(key; 0, j)   (both output words)
//   random_bits(key,32,()) = xor-fold of threefry2x32(key; 0, 0)
// R6 lesson: host CANNOT disambiguate (B,N) from flat sizes — it guessed
// N=40000 and silently fell back to the 46.8us global-chase kernel. N lives
// on device. R7: ONE kernel; host only sizes dynamic LDS from the largest
// candidate N that fits; kernel reads true N,G and branches (grid-uniform)
// between the LDS-resident-table chase and the verified global chase.
//   block = 1024 thr = 16 waves = 16 walks, 256 blocks = 1/CU.
//   A0: wave0 = 16 carry chains (serial floor ~5.5us)  ||  waves1-15 stage
//       nb -> 3x u16[N] in LDS (~120KB, ~3us).  One barrier.
//   walk: 9 wave-uniform ds_read_u16 candidate prefetch/iter (~130cyc/step).

namespace {

__device__ __forceinline__ uint32_t rotl32(uint32_t x, int r) {
  return (x << r) | (x >> (32 - r));
}

// Threefry-2x32, 20 rounds — exactly JAX's threefry2x32_p.
__device__ __forceinline__ void tf2x32(uint32_t ka, uint32_t kb,
                                       uint32_t x0, uint32_t x1,
                                       uint32_t& o0, uint32_t& o1) {
  const uint32_t kc = ka ^ kb ^ 0x1BD11BDAu;
  x0 += ka; x1 += kb;
#define TF_R4(r0, r1, r2, r3)                          \
  x0 += x1; x1 = rotl32(x1, r0); x1 ^= x0;             \
  x0 += x1; x1 = rotl32(x1, r1); x1 ^= x0;             \
  x0 += x1; x1 = rotl32(x1, r2); x1 ^= x0;             \
  x0 += x1; x1 = rotl32(x1, r3); x1 ^= x0;
  TF_R4(13, 15, 26, 6)  x0 += kb; x1 += kc + 1u;
  TF_R4(17, 29, 16, 24) x0 += kc; x1 += ka + 2u;
  TF_R4(13, 15, 26, 6)  x0 += ka; x1 += kb + 3u;
  TF_R4(17, 29, 16, 24) x0 += kb; x1 += kc + 4u;
  TF_R4(13, 15, 26, 6)  x0 += kc; x1 += ka + 5u;
#undef TF_R4
  o0 = x0; o1 = x1;
}

// (hi, lo) bits of jax.random.randint(key, (), 0, span): span-independent.
__device__ __forceinline__ void randbits(uint32_t ka, uint32_t kb,
                                         uint32_t& hi, uint32_t& lo) {
  uint32_t s0a, s0b, s1a, s1b, h0, h1;
  tf2x32(ka, kb, 0u, 0u, s0a, s0b);   // split(key)[0]
  tf2x32(ka, kb, 0u, 1u, s1a, s1b);   // split(key)[1]
  tf2x32(s0a, s0b, 0u, 0u, h0, h1);
  hi = h0 ^ h1;
  tf2x32(s1a, s1b, 0u, 0u, h0, h1);
  lo = h0 ^ h1;
}

__device__ __forceinline__ uint32_t r_generic(uint32_t hi, uint32_t lo,
                                              uint32_t span) {
  uint32_t mult = 65536u % span;
  mult = (mult * mult) % span;
  return ((hi % span) * mult + (lo % span)) % span;
}

// pick code: r3 (span=3 result) in bits 0..1, r2 (span=2 result) in bit 2.
__device__ __forceinline__ uint32_t pick_code(uint32_t hi, uint32_t lo) {
  return ((hi % 3u + lo % 3u) % 3u) | ((lo & 1u) << 2);
}

constexpr int WPB = 16;      // walks per block (one per wave; 1024 threads)
constexpr int CH = 64;       // cached chain length (covers seq_len 63)
constexpr int KSTRIDE = 65;  // keysL stride in uint2 (breaks bank alias)
constexpr size_t KEYS_BYTES = (size_t)WPB * KSTRIDE * sizeof(uint2);  // 8320

__global__ __launch_bounds__(1024) void walk_kernel(
    const float* __restrict__ xyz, const int* __restrict__ nbrs,
    const int* __restrict__ centers, const int* __restrict__ n_faces_p,
    const int* __restrict__ seq_len_p, float* __restrict__ out,
    int s0, int num_walks, int Lp1, unsigned lds_alloc) {
  extern __shared__ char smem[];
  uint2* keysL = (uint2*)smem;                       // [WPB][KSTRIDE]

  const int tid = threadIdx.x;
  const int wv = tid >> 6, lane = tid & 63;
  const int w0 = blockIdx.x * WPB;
  if (w0 >= num_walks) return;                        // block-uniform
  const int w = w0 + wv;
  const bool active = (w < num_walks);

  const int N = *n_faces_p;    // true N (device-only knowledge)
  const int L = *seq_len_p;
  const int B = s0 / (3 * N);
  const int G = num_walks / B;
  const int Npad = (N + 3) & ~3;
  // Grid-uniform decision: LDS table fits AND blocks don't straddle batches.
  const bool lds_ok =
      ((size_t)6 * Npad + KEYS_BYTES <= (size_t)lds_alloc) && (G % WPB == 0);

  uint16_t* nb0L = (uint16_t*)(smem + KEYS_BYTES);
  uint16_t* nb1L = nb0L + Npad;
  uint16_t* nb2L = nb1L + Npad;

  const int bb = (active ? w : w0) / G;
  const int* __restrict__ nb   = nbrs + (size_t)bb * N * 3;
  const float* __restrict__ xb = xyz + (size_t)bb * N * 3;

  const int f0 = active ? centers[w] : 0;
  int3 grow = make_int3(0, 0, 0);
  if (!lds_ok && active)                     // global path: early row load
    grow = *reinterpret_cast<const int3*>(nb + 3 * (size_t)f0);

  // ---- Phase A0: wave 0 = 16 carry chains; waves 1..15 = LDS staging -----
  if (wv == 0) {
    if (lane < WPB && (w0 + lane) < num_walks) {
      uint32_t ka, kb;
      tf2x32(0u, 42u, 0u, (uint32_t)(w0 + lane), ka, kb);  // k_0
      keysL[lane * KSTRIDE + 0] = make_uint2(ka, kb);
#pragma clang loop unroll(disable)
      for (int c = 1; c < CH; ++c) {
        tf2x32(ka, kb, 0u, 0u, ka, kb);
        keysL[lane * KSTRIDE + c] = make_uint2(ka, kb);
      }
    }
  } else if (lds_ok) {
    const int* __restrict__ nbs = nbrs + (size_t)(w0 / G) * N * 3;  // uniform
    for (int r = tid - 64; r < N; r += 960) {
      const int3 v = *reinterpret_cast<const int3*>(nbs + 3 * (size_t)r);
      nb0L[r] = (uint16_t)v.x;
      nb1L[r] = (uint16_t)v.y;
      nb2L[r] = (uint16_t)v.z;
    }
  }
  __syncthreads();
  if (!active) return;

  // ---- Per-step randint tree: lane c = step c (wave-local, no barrier) ---
  const uint2 mykey = keysL[wv * KSTRIDE + lane];
  uint32_t mycode;
  {
    uint32_t k1a, k1b, hi, lo;
    tf2x32(mykey.x, mykey.y, 0u, 1u, k1a, k1b);  // k1 = split(k,4)[1]
    randbits(k1a, k1b, hi, lo);
    mycode = pick_code(hi, lo);
  }

  // ---- Walk state (shared by both loop variants) -------------------------
  int hist  = (lane == 0) ? f0 : -1;   // visited set: lane j = j-th node
  int hist2 = -1;                      // slots 64..127 (overflow; ~never)
  int seqr  = (lane == 0) ? f0 : -1;   // lane t = seq[t]

  uint32_t extka = 0, extkb = 0;
  int extc = -1;  // lazy chain extension beyond CH (only after backtracks)

  auto get_key = [&](int idx, uint32_t& ra, uint32_t& rb) {
    if (idx < CH) {
      const uint2 q = keysL[wv * KSTRIDE + idx]; ra = q.x; rb = q.y;
    } else {
      if (extc < 0) {
        const uint2 q = keysL[wv * KSTRIDE + (CH - 1)];
        extka = q.x; extkb = q.y; extc = CH - 1;
      }
      while (extc < idx) { tf2x32(extka, extkb, 0u, 0u, extka, extkb); ++extc; }
      ra = extka; rb = extkb;
    }
  };

  uint32_t code_next = (uint32_t)__shfl((int)mycode, 0);
  int i = 1, bs = 1, c = 0;

  if (lds_ok) {
    // =================== LDS-resident-table chase =========================
    int n0 = nb0L[f0], n1 = nb1L[f0], n2 = nb2L[f0];
    while (i <= L) {
      const int idx = c; ++c;
      const bool deep = (idx >= CH);
      const uint32_t codeP = code_next;
      code_next = (uint32_t)__shfl((int)mycode, (c < CH) ? c : 0);

      // Prefetch all 3 candidate rows; decide ALU overlaps the LDS flight.
      const int a0 = nb0L[n0], a1 = nb1L[n0], a2 = nb2L[n0];
      const int b0 = nb0L[n1], b1 = nb1L[n1], b2 = nb2L[n1];
      const int c0 = nb0L[n2], c1 = nb1L[n2], c2 = nb2L[n2];

      int v0 = __any(hist == n0), v1 = __any(hist == n1), v2 = __any(hist == n2);
      if (deep) {
        v0 |= __any(hist2 == n0); v1 |= __any(hist2 == n1); v2 |= __any(hist2 == n2);
      }
      const int u0 = 1 - v0, u1 = 1 - v1, u2 = 1 - v2;
      const int cnt = u0 + u1 + u2;

      int to_add;
      int sel = -1;
      bool hit = false;
      int bsf = bs;
      if (cnt > 0) {
        uint32_t code;
        if (!deep) {
          code = codeP;
        } else {
          uint32_t ia, ib, k1a, k1b, hi, lo;
          get_key(idx, ia, ib);
          tf2x32(ia, ib, 0u, 1u, k1a, k1b);
          randbits(k1a, k1b, hi, lo);
          code = pick_code(hi, lo);
        }
        const int r3 = (int)(code & 3u), r2 = (int)((code >> 2) & 1u);
        const int target = (cnt == 3 ? r3 : (cnt == 2 ? r2 : 0)) + 1;
        sel = (u0 == target) ? 0 : ((u0 + u1 == target) ? 1 : 2);
        to_add = (sel == 0) ? n0 : ((sel == 1) ? n1 : n2);
      } else {
        // ---- rare backtrack path (live hashing, bit-exact) ----
        uint32_t kia, kib;
        get_key(idx, kia, kib);
        uint32_t kka, kkb;
        tf2x32(kia, kib, 0u, 2u, kka, kkb);  // k2
        bool found = false;
        int ta = 0, bsc = bs;
        while (!found && i > bsc) {
          uint32_t ca, cb, kpa, kpb;
          tf2x32(kka, kkb, 0u, 0u, ca, cb);
          tf2x32(kka, kkb, 0u, 1u, kpa, kpb);
          const int back = __shfl(seqr, i - bsc - 1);
          const int m0 = nb0L[back], m1 = nb1L[back], m2 = nb2L[back];
          int w0m = __any(hist == m0), w1m = __any(hist == m1), w2m = __any(hist == m2);
          if (deep) {
            w0m |= __any(hist2 == m0); w1m |= __any(hist2 == m1); w2m |= __any(hist2 == m2);
          }
          const int e0 = 1 - w0m, e1 = 1 - w1m, e2 = 1 - w2m;
          const int bc = e0 + e1 + e2;
          if (bc > 0) {
            uint32_t bhi, blo;
            randbits(kpa, kpb, bhi, blo);
            const uint32_t bcode = pick_code(bhi, blo);
            const int r3 = (int)(bcode & 3u), r2 = (int)((bcode >> 2) & 1u);
            const int t2v = (bc == 3 ? r3 : (bc == 2 ? r2 : 0)) + 1;
            ta = (e0 == t2v) ? m0 : ((e0 + e1 == t2v) ? m1 : m2);
            found = true;
          } else {
            bsc += 2;
          }
          kka = ca; kkb = cb;
        }
        if (found) {
          to_add = ta; hit = true; bsf = bsc;
        } else {
          uint32_t k3a, k3b, rhi, rlo;
          tf2x32(kia, kib, 0u, 3u, k3a, k3b);  // k3
          randbits(k3a, k3b, rhi, rlo);
          to_add = (int)r_generic(rhi, rlo, (uint32_t)N);
        }
      }

      int i_new, up;
      if (hit) { i_new = i - bsf; bs = bsf; up = i - 1; }   // splat [i_new,i)
      else     { i_new = i;       bs = 1;   up = i; }
      seqr = (lane >= i_new && lane <= up) ? to_add : seqr;

      const int slot = idx + 1;
      if (slot < CH)          hist  = (lane == slot)      ? to_add : hist;
      else if (slot < 2 * CH) hist2 = (lane == slot - CH) ? to_add : hist2;

      i = i_new + 1;

      if (sel == 0)      { n0 = a0; n1 = a1; n2 = a2; }
      else if (sel == 1) { n0 = b0; n1 = b1; n2 = b2; }
      else if (sel == 2) { n0 = c0; n1 = c1; n2 = c2; }
      else { n0 = nb0L[to_add]; n1 = nb1L[to_add]; n2 = nb2L[to_add]; }
    }
  } else {
    // =================== global-chase fallback (verified R5) ==============
    int3 row = grow;
    while (i <= L) {
      const int idx = c; ++c;
      const bool deep = (idx >= CH);
      const uint32_t codeP = code_next;
      code_next = (uint32_t)__shfl((int)mycode, (c < CH) ? c : 0);

      const int n0 = row.x, n1 = row.y, n2 = row.z;
      int v0 = __any(hist == n0), v1 = __any(hist == n1), v2 = __any(hist == n2);
      if (deep) {
        v0 |= __any(hist2 == n0); v1 |= __any(hist2 == n1); v2 |= __any(hist2 == n2);
      }
      const int u0 = 1 - v0, u1 = 1 - v1, u2 = 1 - v2;
      const int cnt = u0 + u1 + u2;

      int to_add;
      bool hit = false;
      int bsf = bs;
      if (cnt > 0) {
        uint32_t code;
        if (!deep) {
          code = codeP;
        } else {
          uint32_t ia, ib, k1a, k1b, hi, lo;
          get_key(idx, ia, ib);
          tf2x32(ia, ib, 0u, 1u, k1a, k1b);
          randbits(k1a, k1b, hi, lo);
          code = pick_code(hi, lo);
        }
        const int r3 = (int)(code & 3u), r2 = (int)((code >> 2) & 1u);
        const int target = (cnt == 3 ? r3 : (cnt == 2 ? r2 : 0)) + 1;
        to_add = (u0 == target) ? n0 : ((u0 + u1 == target) ? n1 : n2);
      } else {
        uint32_t kia, kib;
        get_key(idx, kia, kib);
        uint32_t kka, kkb;
        tf2x32(kia, kib, 0u, 2u, kka, kkb);
        bool found = false;
        int ta = 0, bsc = bs;
        while (!found && i > bsc) {
          uint32_t ca, cb, kpa, kpb;
          tf2x32(kka, kkb, 0u, 0u, ca, cb);
          tf2x32(kka, kkb, 0u, 1u, kpa, kpb);
          const int back = __shfl(seqr, i - bsc - 1);
          const int3 br = *reinterpret_cast<const int3*>(nb + 3 * (size_t)back);
          int w0m = __any(hist == br.x), w1m = __any(hist == br.y), w2m = __any(hist == br.z);
          if (deep) {
            w0m |= __any(hist2 == br.x); w1m |= __any(hist2 == br.y); w2m |= __any(hist2 == br.z);
          }
          const int e0 = 1 - w0m, e1 = 1 - w1m, e2 = 1 - w2m;
          const int bc = e0 + e1 + e2;
          if (bc > 0) {
            uint32_t bhi, blo;
            randbits(kpa, kpb, bhi, blo);
            const uint32_t bcode = pick_code(bhi, blo);
            const int r3 = (int)(bcode & 3u), r2 = (int)((bcode >> 2) & 1u);
            const int t2v = (bc == 3 ? r3 : (bc == 2 ? r2 : 0)) + 1;
            ta = (e0 == t2v) ? br.x : ((e0 + e1 == t2v) ? br.y : br.z);
            found = true;
          } else {
            bsc += 2;
          }
          kka = ca; kkb = cb;
        }
        if (found) {
          to_add = ta; hit = true; bsf = bsc;
        } else {
          uint32_t k3a, k3b, rhi, rlo;
          tf2x32(kia, kib, 0u, 3u, k3a, k3b);
          randbits(k3a, k3b, rhi, rlo);
          to_add = (int)r_generic(rhi, rlo, (uint32_t)N);
        }
      }

      int i_new, up;
      if (hit) { i_new = i - bsf; bs = bsf; up = i - 1; }
      else     { i_new = i;       bs = 1;   up = i; }
      seqr = (lane >= i_new && lane <= up) ? to_add : seqr;

      const int slot = idx + 1;
      if (slot < CH)          hist  = (lane == slot)      ? to_add : hist;
      else if (slot < 2 * CH) hist2 = (lane == slot - CH) ? to_add : hist2;

      i = i_new + 1;
      row = *reinterpret_cast<const int3*>(nb + 3 * (size_t)to_add);
    }
  }

  // ---- Epilogue: lane t holds seq[t] ------------------------------------
  const float cx = xb[3 * (size_t)f0 + 0];
  const float cy = xb[3 * (size_t)f0 + 1];
  const float cz = xb[3 * (size_t)f0 + 2];
  if (lane < Lp1) {
    const int node = seqr;
    float3 v;
    v.x = xb[3 * (size_t)node + 0] - cx;
    v.y = xb[3 * (size_t)node + 1] - cy;
    v.z = xb[3 * (size_t)node + 2] - cz;
    *reinterpret_cast<float3*>(out + ((size_t)w * Lp1 + lane) * 3) = v;
  }
}

}  // namespace

extern "C" void kernel_launch(void* const* d_in, const int* in_sizes, int n_in,
                              void* d_out, int out_size, void* d_ws, size_t ws_size,
                              hipStream_t stream) {
  const float* xyz     = (const float*)d_in[0];
  const int*   nbrs    = (const int*)d_in[1];
  const int*   centers = (const int*)d_in[2];
  const int*   n_faces = (const int*)d_in[3];
  const int*   seq_len = (const int*)d_in[4];
  float* out = (float*)d_out;

  const int s0 = in_sizes[0];                  // B*N*3
  const int num_walks = in_sizes[2];           // B*G
  const int Lp1 = out_size / (3 * num_walks);  // seq_len+1

  // Host cannot know N (B·N only); size the dynamic LDS from the LARGEST
  // candidate N that fits. Kernel validates against true N and falls back
  // internally — a wrong guess is a perf choice, never a correctness one.
  const size_t lds_cap = 160 * 1024 - 2048;
  size_t lds_bytes = KEYS_BYTES;
  int bestN = -1;
  for (int Bc = 1; Bc <= num_walks; ++Bc) {
    if (num_walks % Bc) continue;
    if (s0 % (3 * Bc)) continue;
    const int Nc = s0 / (3 * Bc);
    const int Gc = num_walks / Bc;
    if (Nc > 65535 || (Gc % WPB)) continue;
    const size_t need = KEYS_BYTES + (size_t)6 * ((Nc + 3) & ~3);
    if (need <= lds_cap && Nc > bestN) bestN = Nc;
  }
  if (bestN > 0)
    lds_bytes = KEYS_BYTES + (size_t)6 * ((bestN + 3) & ~3);

  if (lds_bytes > 64 * 1024) {
    hipError_t e = hipFuncSetAttribute(
        (const void*)walk_kernel,
        hipFuncAttributeMaxDynamicSharedMemorySize, (int)lds_bytes);
    if (e != hipSuccess) lds_bytes = KEYS_BYTES;  // global path only
  }

  const int blocks = (num_walks + WPB - 1) / WPB;
  walk_kernel<<<blocks, WPB * 64, lds_bytes, stream>>>(
      xyz, nbrs, centers, n_faces, seq_len, out, s0, num_walks, Lp1,
      (unsigned)lds_bytes);
}

// Round 8
// 107.508 us; speedup vs baseline: 1.0030x; 1.0030x over previous
//
#include <hip/hip_runtime.h>
#include <stdint.h>
#include <stddef.h>

// MambaMesh random-walk + gather-recenter.  R8: STATIC-LDS neighbor table.
// PRNG (bit-exact vs JAX partitionable Threefry, verified R1-R7, absmax 0.0):
//   split(key,n)[j]        = threefry2x32(key; 0, j)   (both output words)
//   random_bits(key,32,()) = xor-fold of threefry2x32(key; 0, 0)
// R7 lesson: hipFuncSetAttribute(MaxDynamicSharedMemorySize) failed on this
// ROCm -> silent fallback to the 51us global chase (dur == R3, LDS_Block=0).
// R8: static __shared__ (no opt-in API): nb packed u32(n0|n1)+u16(n2) for
// N<=20480 = 120KB + 8.3KB keys = 131.2KB < 160KB gfx950 LDS. Device picks
// LDS path iff N<=NMAX && G%WPB==0, else verified global chase.
//   block = 1024 thr = 16 waves = 16 walks, 256 blocks = 1 block/CU.
//   A0: wave0 = 16 carry chains || waves1-15 stage nb -> LDS. One barrier.
//   walk: 6 wave-uniform ds_read candidate prefetch/iter + decide overlap.

namespace {

__device__ __forceinline__ uint32_t rotl32(uint32_t x, int r) {
  return (x << r) | (x >> (32 - r));
}

// Threefry-2x32, 20 rounds — exactly JAX's threefry2x32_p.
__device__ __forceinline__ void tf2x32(uint32_t ka, uint32_t kb,
                                       uint32_t x0, uint32_t x1,
                                       uint32_t& o0, uint32_t& o1) {
  const uint32_t kc = ka ^ kb ^ 0x1BD11BDAu;
  x0 += ka; x1 += kb;
#define TF_R4(r0, r1, r2, r3)                          \
  x0 += x1; x1 = rotl32(x1, r0); x1 ^= x0;             \
  x0 += x1; x1 = rotl32(x1, r1); x1 ^= x0;             \
  x0 += x1; x1 = rotl32(x1, r2); x1 ^= x0;             \
  x0 += x1; x1 = rotl32(x1, r3); x1 ^= x0;
  TF_R4(13, 15, 26, 6)  x0 += kb; x1 += kc + 1u;
  TF_R4(17, 29, 16, 24) x0 += kc; x1 += ka + 2u;
  TF_R4(13, 15, 26, 6)  x0 += ka; x1 += kb + 3u;
  TF_R4(17, 29, 16, 24) x0 += kb; x1 += kc + 4u;
  TF_R4(13, 15, 26, 6)  x0 += kc; x1 += ka + 5u;
#undef TF_R4
  o0 = x0; o1 = x1;
}

// (hi, lo) bits of jax.random.randint(key, (), 0, span): span-independent.
__device__ __forceinline__ void randbits(uint32_t ka, uint32_t kb,
                                         uint32_t& hi, uint32_t& lo) {
  uint32_t s0a, s0b, s1a, s1b, h0, h1;
  tf2x32(ka, kb, 0u, 0u, s0a, s0b);   // split(key)[0]
  tf2x32(ka, kb, 0u, 1u, s1a, s1b);   // split(key)[1]
  tf2x32(s0a, s0b, 0u, 0u, h0, h1);
  hi = h0 ^ h1;
  tf2x32(s1a, s1b, 0u, 0u, h0, h1);
  lo = h0 ^ h1;
}

__device__ __forceinline__ uint32_t r_generic(uint32_t hi, uint32_t lo,
                                              uint32_t span) {
  uint32_t mult = 65536u % span;
  mult = (mult * mult) % span;
  return ((hi % span) * mult + (lo % span)) % span;
}

// pick code: r3 (span=3 result) in bits 0..1, r2 (span=2 result) in bit 2.
__device__ __forceinline__ uint32_t pick_code(uint32_t hi, uint32_t lo) {
  return ((hi % 3u + lo % 3u) % 3u) | ((lo & 1u) << 2);
}

constexpr int WPB = 16;      // walks per block (one per wave; 1024 threads)
constexpr int CH = 64;       // cached chain length (covers seq_len 63)
constexpr int KSTRIDE = 65;  // keysL stride in uint2 (breaks bank alias)
constexpr int NMAX = 20480;  // LDS-table capacity (rows)

__global__ __launch_bounds__(1024) void walk_kernel(
    const float* __restrict__ xyz, const int* __restrict__ nbrs,
    const int* __restrict__ centers, const int* __restrict__ n_faces_p,
    const int* __restrict__ seq_len_p, float* __restrict__ out,
    int s0, int num_walks, int Lp1) {
  // Static LDS: 80KB + 40KB + 8.3KB = 131,200 B (gfx950 has 160KB).
  __shared__ uint32_t nb01L[NMAX];          // n0 | n1<<16
  __shared__ uint16_t nb2L[NMAX];           // n2
  __shared__ uint2 keysL[WPB * KSTRIDE];    // carry keys per walk/step

  const int tid = threadIdx.x;
  const int wv = tid >> 6, lane = tid & 63;
  const int w0 = blockIdx.x * WPB;
  if (w0 >= num_walks) return;               // block-uniform
  const int w = w0 + wv;
  const bool active = (w < num_walks);

  const int N = *n_faces_p;    // true N (device-only knowledge)
  const int L = *seq_len_p;
  const int B = s0 / (3 * N);
  const int G = num_walks / B;
  // Grid-uniform decision: table fits AND blocks don't straddle batches.
  const bool lds_ok = (N <= NMAX) && (G % WPB == 0);

  const int bb = (active ? w : w0) / G;
  const int* __restrict__ nb   = nbrs + (size_t)bb * N * 3;
  const float* __restrict__ xb = xyz + (size_t)bb * N * 3;

  const int f0 = active ? centers[w] : 0;
  int3 grow = make_int3(0, 0, 0);
  if (!lds_ok && active)                     // global path: early row load
    grow = *reinterpret_cast<const int3*>(nb + 3 * (size_t)f0);

  // ---- Phase A0: wave 0 = 16 carry chains; waves 1..15 = LDS staging -----
  if (wv == 0) {
    if (lane < WPB && (w0 + lane) < num_walks) {
      uint32_t ka, kb;
      tf2x32(0u, 42u, 0u, (uint32_t)(w0 + lane), ka, kb);  // k_0
      keysL[lane * KSTRIDE + 0] = make_uint2(ka, kb);
#pragma clang loop unroll(disable)
      for (int c = 1; c < CH; ++c) {
        tf2x32(ka, kb, 0u, 0u, ka, kb);
        keysL[lane * KSTRIDE + c] = make_uint2(ka, kb);
      }
    }
  } else if (lds_ok) {
    const int* __restrict__ nbs = nbrs + (size_t)(w0 / G) * N * 3;  // uniform
    for (int r = tid - 64; r < N; r += 960) {
      const int3 v = *reinterpret_cast<const int3*>(nbs + 3 * (size_t)r);
      nb01L[r] = (uint32_t)v.x | ((uint32_t)v.y << 16);
      nb2L[r]  = (uint16_t)v.z;
    }
  }
  __syncthreads();
  if (!active) return;

  // ---- Per-step randint tree: lane c = step c (wave-local, no barrier) ---
  const uint2 mykey = keysL[wv * KSTRIDE + lane];
  uint32_t mycode;
  {
    uint32_t k1a, k1b, hi, lo;
    tf2x32(mykey.x, mykey.y, 0u, 1u, k1a, k1b);  // k1 = split(k,4)[1]
    randbits(k1a, k1b, hi, lo);
    mycode = pick_code(hi, lo);
  }

  // ---- Walk state (shared by both loop variants) -------------------------
  int hist  = (lane == 0) ? f0 : -1;   // visited set: lane j = j-th node
  int hist2 = -1;                      // slots 64..127 (overflow; ~never)
  int seqr  = (lane == 0) ? f0 : -1;   // lane t = seq[t]

  uint32_t extka = 0, extkb = 0;
  int extc = -1;  // lazy chain extension beyond CH (only after backtracks)

  auto get_key = [&](int idx, uint32_t& ra, uint32_t& rb) {
    if (idx < CH) {
      const uint2 q = keysL[wv * KSTRIDE + idx]; ra = q.x; rb = q.y;
    } else {
      if (extc < 0) {
        const uint2 q = keysL[wv * KSTRIDE + (CH - 1)];
        extka = q.x; extkb = q.y; extc = CH - 1;
      }
      while (extc < idx) { tf2x32(extka, extkb, 0u, 0u, extka, extkb); ++extc; }
      ra = extka; rb = extkb;
    }
  };

  uint32_t code_next = (uint32_t)__shfl((int)mycode, 0);
  int i = 1, bs = 1, c = 0;

  if (lds_ok) {
    // =================== LDS-resident-table chase =========================
    uint32_t p0 = nb01L[f0];
    int n0 = (int)(p0 & 0xffffu), n1 = (int)(p0 >> 16), n2 = (int)nb2L[f0];
    while (i <= L) {
      const int idx = c; ++c;
      const bool deep = (idx >= CH);
      const uint32_t codeP = code_next;
      code_next = (uint32_t)__shfl((int)mycode, (c < CH) ? c : 0);

      // Prefetch all 3 candidate rows (6 ds_reads); decide overlaps flight.
      const uint32_t pA = nb01L[n0]; const int a2v = (int)nb2L[n0];
      const uint32_t pB = nb01L[n1]; const int b2v = (int)nb2L[n1];
      const uint32_t pC = nb01L[n2]; const int c2v = (int)nb2L[n2];

      int v0 = __any(hist == n0), v1 = __any(hist == n1), v2 = __any(hist == n2);
      if (deep) {
        v0 |= __any(hist2 == n0); v1 |= __any(hist2 == n1); v2 |= __any(hist2 == n2);
      }
      const int u0 = 1 - v0, u1 = 1 - v1, u2 = 1 - v2;
      const int cnt = u0 + u1 + u2;

      int to_add;
      int sel = -1;
      bool hit = false;
      int bsf = bs;
      if (cnt > 0) {
        uint32_t code;
        if (!deep) {
          code = codeP;
        } else {  // rare: live tree beyond cached steps
          uint32_t ia, ib, k1a, k1b, hi, lo;
          get_key(idx, ia, ib);
          tf2x32(ia, ib, 0u, 1u, k1a, k1b);
          randbits(k1a, k1b, hi, lo);
          code = pick_code(hi, lo);
        }
        const int r3 = (int)(code & 3u), r2 = (int)((code >> 2) & 1u);
        const int target = (cnt == 3 ? r3 : (cnt == 2 ? r2 : 0)) + 1;
        sel = (u0 == target) ? 0 : ((u0 + u1 == target) ? 1 : 2);
        to_add = (sel == 0) ? n0 : ((sel == 1) ? n1 : n2);
      } else {
        // ---- rare backtrack path (live hashing, bit-exact) ----
        uint32_t kia, kib;
        get_key(idx, kia, kib);
        uint32_t kka, kkb;
        tf2x32(kia, kib, 0u, 2u, kka, kkb);  // k2
        bool found = false;
        int ta = 0, bsc = bs;
        while (!found && i > bsc) {
          uint32_t ca, cb, kpa, kpb;
          tf2x32(kka, kkb, 0u, 0u, ca, cb);
          tf2x32(kka, kkb, 0u, 1u, kpa, kpb);
          const int back = __shfl(seqr, i - bsc - 1);
          const uint32_t pm = nb01L[back];
          const int m0 = (int)(pm & 0xffffu), m1 = (int)(pm >> 16);
          const int m2 = (int)nb2L[back];
          int w0m = __any(hist == m0), w1m = __any(hist == m1), w2m = __any(hist == m2);
          if (deep) {
            w0m |= __any(hist2 == m0); w1m |= __any(hist2 == m1); w2m |= __any(hist2 == m2);
          }
          const int e0 = 1 - w0m, e1 = 1 - w1m, e2 = 1 - w2m;
          const int bc = e0 + e1 + e2;
          if (bc > 0) {
            uint32_t bhi, blo;
            randbits(kpa, kpb, bhi, blo);
            const uint32_t bcode = pick_code(bhi, blo);
            const int r3 = (int)(bcode & 3u), r2 = (int)((bcode >> 2) & 1u);
            const int t2v = (bc == 3 ? r3 : (bc == 2 ? r2 : 0)) + 1;
            ta = (e0 == t2v) ? m0 : ((e0 + e1 == t2v) ? m1 : m2);
            found = true;
          } else {
            bsc += 2;
          }
          kka = ca; kkb = cb;
        }
        if (found) {
          to_add = ta; hit = true; bsf = bsc;
        } else {
          uint32_t k3a, k3b, rhi, rlo;
          tf2x32(kia, kib, 0u, 3u, k3a, k3b);  // k3
          randbits(k3a, k3b, rhi, rlo);
          to_add = (int)r_generic(rhi, rlo, (uint32_t)N);
        }
      }

      int i_new, up;
      if (hit) { i_new = i - bsf; bs = bsf; up = i - 1; }   // splat [i_new,i)
      else     { i_new = i;       bs = 1;   up = i; }
      seqr = (lane >= i_new && lane <= up) ? to_add : seqr;

      const int slot = idx + 1;
      if (slot < CH)          hist  = (lane == slot)      ? to_add : hist;
      else if (slot < 2 * CH) hist2 = (lane == slot - CH) ? to_add : hist2;

      i = i_new + 1;

      if (sel == 0)      { n0 = (int)(pA & 0xffffu); n1 = (int)(pA >> 16); n2 = a2v; }
      else if (sel == 1) { n0 = (int)(pB & 0xffffu); n1 = (int)(pB >> 16); n2 = b2v; }
      else if (sel == 2) { n0 = (int)(pC & 0xffffu); n1 = (int)(pC >> 16); n2 = c2v; }
      else {
        const uint32_t p = nb01L[to_add];
        n0 = (int)(p & 0xffffu); n1 = (int)(p >> 16); n2 = (int)nb2L[to_add];
      }
    }
  } else {
    // =================== global-chase fallback (verified R5) ==============
    int3 row = grow;
    while (i <= L) {
      const int idx = c; ++c;
      const bool deep = (idx >= CH);
      const uint32_t codeP = code_next;
      code_next = (uint32_t)__shfl((int)mycode, (c < CH) ? c : 0);

      const int n0 = row.x, n1 = row.y, n2 = row.z;
      int v0 = __any(hist == n0), v1 = __any(hist == n1), v2 = __any(hist == n2);
      if (deep) {
        v0 |= __any(hist2 == n0); v1 |= __any(hist2 == n1); v2 |= __any(hist2 == n2);
      }
      const int u0 = 1 - v0, u1 = 1 - v1, u2 = 1 - v2;
      const int cnt = u0 + u1 + u2;

      int to_add;
      bool hit = false;
      int bsf = bs;
      if (cnt > 0) {
        uint32_t code;
        if (!deep) {
          code = codeP;
        } else {
          uint32_t ia, ib, k1a, k1b, hi, lo;
          get_key(idx, ia, ib);
          tf2x32(ia, ib, 0u, 1u, k1a, k1b);
          randbits(k1a, k1b, hi, lo);
          code = pick_code(hi, lo);
        }
        const int r3 = (int)(code & 3u), r2 = (int)((code >> 2) & 1u);
        const int target = (cnt == 3 ? r3 : (cnt == 2 ? r2 : 0)) + 1;
        to_add = (u0 == target) ? n0 : ((u0 + u1 == target) ? n1 : n2);
      } else {
        uint32_t kia, kib;
        get_key(idx, kia, kib);
        uint32_t kka, kkb;
        tf2x32(kia, kib, 0u, 2u, kka, kkb);
        bool found = false;
        int ta = 0, bsc = bs;
        while (!found && i > bsc) {
          uint32_t ca, cb, kpa, kpb;
          tf2x32(kka, kkb, 0u, 0u, ca, cb);
          tf2x32(kka, kkb, 0u, 1u, kpa, kpb);
          const int back = __shfl(seqr, i - bsc - 1);
          const int3 br = *reinterpret_cast<const int3*>(nb + 3 * (size_t)back);
          int w0m = __any(hist == br.x), w1m = __any(hist == br.y), w2m = __any(hist == br.z);
          if (deep) {
            w0m |= __any(hist2 == br.x); w1m |= __any(hist2 == br.y); w2m |= __any(hist2 == br.z);
          }
          const int e0 = 1 - w0m, e1 = 1 - w1m, e2 = 1 - w2m;
          const int bc = e0 + e1 + e2;
          if (bc > 0) {
            uint32_t bhi, blo;
            randbits(kpa, kpb, bhi, blo);
            const uint32_t bcode = pick_code(bhi, blo);
            const int r3 = (int)(bcode & 3u), r2 = (int)((bcode >> 2) & 1u);
            const int t2v = (bc == 3 ? r3 : (bc == 2 ? r2 : 0)) + 1;
            ta = (e0 == t2v) ? br.x : ((e0 + e1 == t2v) ? br.y : br.z);
            found = true;
          } else {
            bsc += 2;
          }
          kka = ca; kkb = cb;
        }
        if (found) {
          to_add = ta; hit = true; bsf = bsc;
        } else {
          uint32_t k3a, k3b, rhi, rlo;
          tf2x32(kia, kib, 0u, 3u, k3a, k3b);
          randbits(k3a, k3b, rhi, rlo);
          to_add = (int)r_generic(rhi, rlo, (uint32_t)N);
        }
      }

      int i_new, up;
      if (hit) { i_new = i - bsf; bs = bsf; up = i - 1; }
      else     { i_new = i;       bs = 1;   up = i; }
      seqr = (lane >= i_new && lane <= up) ? to_add : seqr;

      const int slot = idx + 1;
      if (slot < CH)          hist  = (lane == slot)      ? to_add : hist;
      else if (slot < 2 * CH) hist2 = (lane == slot - CH) ? to_add : hist2;

      i = i_new + 1;
      row = *reinterpret_cast<const int3*>(nb + 3 * (size_t)to_add);
    }
  }

  // ---- Epilogue: lane t holds seq[t] ------------------------------------
  const float cx = xb[3 * (size_t)f0 + 0];
  const float cy = xb[3 * (size_t)f0 + 1];
  const float cz = xb[3 * (size_t)f0 + 2];
  if (lane < Lp1) {
    const int node = seqr;
    float3 v;
    v.x = xb[3 * (size_t)node + 0] - cx;
    v.y = xb[3 * (size_t)node + 1] - cy;
    v.z = xb[3 * (size_t)node + 2] - cz;
    *reinterpret_cast<float3*>(out + ((size_t)w * Lp1 + lane) * 3) = v;
  }
}

}  // namespace

extern "C" void kernel_launch(void* const* d_in, const int* in_sizes, int n_in,
                              void* d_out, int out_size, void* d_ws, size_t ws_size,
                              hipStream_t stream) {
  const float* xyz     = (const float*)d_in[0];
  const int*   nbrs    = (const int*)d_in[1];
  const int*   centers = (const int*)d_in[2];
  const int*   n_faces = (const int*)d_in[3];
  const int*   seq_len = (const int*)d_in[4];
  float* out = (float*)d_out;

  const int s0 = in_sizes[0];                  // B*N*3
  const int num_walks = in_sizes[2];           // B*G
  const int Lp1 = out_size / (3 * num_walks);  // seq_len+1

  const int blocks = (num_walks + WPB - 1) / WPB;
  walk_kernel<<<blocks, WPB * 64, 0, stream>>>(
      xyz, nbrs, centers, n_faces, seq_len, out, s0, num_walks, Lp1);
}

// Round 9
// 99.697 us; speedup vs baseline: 1.0816x; 1.0784x over previous
//
#include <hip/hip_runtime.h>
#include <stdint.h>
#include <stddef.h>

// MambaMesh random-walk + gather-recenter.  R9: LDS bitmap visited-set.
// PRNG (bit-exact vs JAX partitionable Threefry, verified R1-R8, absmax 0.0):
//   split(key,n)[j]        = threefry2x32(key; 0, j)   (both output words)
//   random_bits(key,32,()) = xor-fold of threefry2x32(key; 0, 0)
// R8 lesson (decisive): LDS-table chase ran (LDS_Block=131584) and was NOT
// faster -> the wall is the per-iter serial decision machinery (~600 cyc:
// __any vcc->SALU round trips, ~8 branches, hist cndmask updates), not
// memory. R9 deletes that machinery: per-walk visited BITMAP in LDS (exact
// for all N; kills __any/hist/hist2/deep entirely). Per iter: 9 wave-uniform
// ds_reads (3 packed rows + 3 vis words, broadcast) + ~20 ALU + 1 cold test.
//   block = 1024 thr = 16 waves = 16 walks; 1 block/CU.
//   LDS: table 6*NMAX + 16 bitmaps = 162,816 B (<=163,840 HW max; static).
//   keys handoff reuses bitmap region as scratch before zeroing (2 barriers).

namespace {

__device__ __forceinline__ uint32_t rotl32(uint32_t x, int r) {
  return (x << r) | (x >> (32 - r));
}

// Threefry-2x32, 20 rounds — exactly JAX's threefry2x32_p.
__device__ __forceinline__ void tf2x32(uint32_t ka, uint32_t kb,
                                       uint32_t x0, uint32_t x1,
                                       uint32_t& o0, uint32_t& o1) {
  const uint32_t kc = ka ^ kb ^ 0x1BD11BDAu;
  x0 += ka; x1 += kb;
#define TF_R4(r0, r1, r2, r3)                          \
  x0 += x1; x1 = rotl32(x1, r0); x1 ^= x0;             \
  x0 += x1; x1 = rotl32(x1, r1); x1 ^= x0;             \
  x0 += x1; x1 = rotl32(x1, r2); x1 ^= x0;             \
  x0 += x1; x1 = rotl32(x1, r3); x1 ^= x0;
  TF_R4(13, 15, 26, 6)  x0 += kb; x1 += kc + 1u;
  TF_R4(17, 29, 16, 24) x0 += kc; x1 += ka + 2u;
  TF_R4(13, 15, 26, 6)  x0 += ka; x1 += kb + 3u;
  TF_R4(17, 29, 16, 24) x0 += kb; x1 += kc + 4u;
  TF_R4(13, 15, 26, 6)  x0 += kc; x1 += ka + 5u;
#undef TF_R4
  o0 = x0; o1 = x1;
}

// (hi, lo) bits of jax.random.randint(key, (), 0, span): span-independent.
__device__ __forceinline__ void randbits(uint32_t ka, uint32_t kb,
                                         uint32_t& hi, uint32_t& lo) {
  uint32_t s0a, s0b, s1a, s1b, h0, h1;
  tf2x32(ka, kb, 0u, 0u, s0a, s0b);   // split(key)[0]
  tf2x32(ka, kb, 0u, 1u, s1a, s1b);   // split(key)[1]
  tf2x32(s0a, s0b, 0u, 0u, h0, h1);
  hi = h0 ^ h1;
  tf2x32(s1a, s1b, 0u, 0u, h0, h1);
  lo = h0 ^ h1;
}

__device__ __forceinline__ uint32_t r_generic(uint32_t hi, uint32_t lo,
                                              uint32_t span) {
  uint32_t mult = 65536u % span;
  mult = (mult * mult) % span;
  return ((hi % span) * mult + (lo % span)) % span;
}

// pick code: r3 (span=3 result) in bits 0..1, r2 (span=2 result) in bit 2.
__device__ __forceinline__ uint32_t pick_code(uint32_t hi, uint32_t lo) {
  return ((hi % 3u + lo % 3u) % 3u) | ((lo & 1u) << 2);
}

constexpr int WPB = 16;       // walks per block (one per wave; 1024 threads)
constexpr int CH = 64;        // cached chain length (covers seq_len 63)
constexpr int NMAX = 20352;   // LDS-table capacity (rows)
constexpr int VISW = 636;     // bitmap words per walk = ceil(NMAX/32)

__global__ __launch_bounds__(1024) void walk_kernel(
    const float* __restrict__ xyz, const int* __restrict__ nbrs,
    const int* __restrict__ centers, const int* __restrict__ n_faces_p,
    const int* __restrict__ seq_len_p, float* __restrict__ out,
    int s0, int num_walks, int Lp1) {
  // Static LDS: 81,408 + 40,704 + 40,704 = 162,816 B (HW max 163,840).
  __shared__ uint32_t nb01L[NMAX];        // n0 | n1<<16
  __shared__ uint16_t nb2L[NMAX];         // n2
  __shared__ uint32_t visL[WPB * VISW];   // bitmaps; pre-zero: keys scratch

  const int tid = threadIdx.x;
  const int wv = tid >> 6, lane = tid & 63;
  const int w0 = blockIdx.x * WPB;
  if (w0 >= num_walks) return;             // block-uniform
  const int w = w0 + wv;
  const bool active = (w < num_walks);

  const int N = *n_faces_p;
  const int L = *seq_len_p;
  const int B = s0 / (3 * N);
  const int G = num_walks / B;
  const bool lds_ok = (N <= NMAX) && (G % WPB == 0);   // grid-uniform

  const int bb = (active ? w : w0) / G;
  const int* __restrict__ nb   = nbrs + (size_t)bb * N * 3;
  const float* __restrict__ xb = xyz + (size_t)bb * N * 3;

  const int f0 = active ? centers[w] : 0;
  int3 grow = make_int3(0, 0, 0);
  if (!lds_ok && active)                   // global path: early row load
    grow = *reinterpret_cast<const int3*>(nb + 3 * (size_t)f0);

  // ---- Phase A0: wave 0 = 16 carry chains (keys -> visL scratch);
  //      waves 1..15 = table staging (lds_ok only). ------------------------
  if (wv == 0) {
    if (lane < WPB && (w0 + lane) < num_walks) {
      uint32_t ka, kb;
      tf2x32(0u, 42u, 0u, (uint32_t)(w0 + lane), ka, kb);  // k_0
      visL[(lane * CH + 0) * 2 + 0] = ka;
      visL[(lane * CH + 0) * 2 + 1] = kb;
#pragma clang loop unroll(disable)
      for (int c2 = 1; c2 < CH; ++c2) {
        tf2x32(ka, kb, 0u, 0u, ka, kb);
        visL[(lane * CH + c2) * 2 + 0] = ka;
        visL[(lane * CH + c2) * 2 + 1] = kb;
      }
    }
  } else if (lds_ok) {
    for (int r = tid - 64; r < N; r += 960) {
      const int3 v = *reinterpret_cast<const int3*>(nb + 3 * (size_t)r);
      nb01L[r] = (uint32_t)v.x | ((uint32_t)v.y << 16);
      nb2L[r]  = (uint16_t)v.z;
    }
  }
  __syncthreads();   // barrier 1: keys + table staged

  // ---- Per-step key/code: lane c = step c (from scratch, wave-local) -----
  const uint32_t mka = visL[(wv * CH + lane) * 2 + 0];
  const uint32_t mkb = visL[(wv * CH + lane) * 2 + 1];
  uint32_t mycode;
  {
    uint32_t k1a, k1b, hi, lo;
    tf2x32(mka, mkb, 0u, 1u, k1a, k1b);   // k1 = split(k,4)[1]
    randbits(k1a, k1b, hi, lo);
    mycode = pick_code(hi, lo);
  }
  __syncthreads();   // barrier 2: all scratch reads done; bitmaps reusable

  if (!active) return;

  uint32_t extka = 0, extkb = 0;
  int extc = -1;     // lazy chain extension beyond CH (only after backtracks)
  auto get_key = [&](int idx, uint32_t& ra, uint32_t& rb) {
    if (idx < CH) {
      ra = (uint32_t)__shfl((int)mka, idx);
      rb = (uint32_t)__shfl((int)mkb, idx);
    } else {
      if (extc < 0) {
        extka = (uint32_t)__shfl((int)mka, CH - 1);
        extkb = (uint32_t)__shfl((int)mkb, CH - 1);
        extc = CH - 1;
      }
      while (extc < idx) { tf2x32(extka, extkb, 0u, 0u, extka, extkb); ++extc; }
      ra = extka; rb = extkb;
    }
  };

  int seqr = (lane == 0) ? f0 : -1;       // lane t = seq[t]
  uint32_t code_next = (uint32_t)__shfl((int)mycode, 0);
  int i = 1, bs = 1, c = 0;

  if (lds_ok) {
    // =================== LDS table + LDS bitmap chase =====================
    uint32_t* __restrict__ visW = visL + wv * VISW;
    // Wave-local zero of OWN bitmap (in-order DS; no barrier needed).
    for (int j = lane; j < VISW; j += 64) visW[j] = 0u;
    if (lane == 0) visW[(unsigned)f0 >> 5] = 1u << (f0 & 31);

    uint32_t p0 = nb01L[f0];
    int n0 = (int)(p0 & 0xffffu), n1 = (int)(p0 >> 16), n2 = (int)nb2L[f0];

    while (i <= L) {
      const int idx = c; ++c;
      // 9 wave-uniform LDS reads issued together (broadcast, conflict-free).
      const uint32_t pA = nb01L[n0]; const uint32_t a2 = nb2L[n0];
      const uint32_t pB = nb01L[n1]; const uint32_t b2 = nb2L[n1];
      const uint32_t pC = nb01L[n2]; const uint32_t c2v = nb2L[n2];
      const uint32_t wv0 = visW[(unsigned)n0 >> 5];
      const uint32_t wv1 = visW[(unsigned)n1 >> 5];
      const uint32_t wv2 = visW[(unsigned)n2 >> 5];
      const uint32_t codeP = code_next;
      code_next = (uint32_t)__shfl((int)mycode, (c < CH) ? c : 0);

      const uint32_t u0 = ((wv0 >> (n0 & 31)) & 1u) ^ 1u;
      const uint32_t u1 = ((wv1 >> (n1 & 31)) & 1u) ^ 1u;
      const uint32_t u2 = ((wv2 >> (n2 & 31)) & 1u) ^ 1u;
      const uint32_t cnt = u0 + u1 + u2;

      int to_add, sel;
      if (__builtin_expect(cnt == 0, 0)) {
        // ---- rare backtrack path (live hashing, bit-exact) ----
        sel = -1;
        uint32_t kia, kib;
        get_key(idx, kia, kib);
        uint32_t kka, kkb;
        tf2x32(kia, kib, 0u, 2u, kka, kkb);  // k2
        bool found = false;
        int ta = 0, bsc = bs;
        while (!found && i > bsc) {
          uint32_t ca, cb, kpa, kpb;
          tf2x32(kka, kkb, 0u, 0u, ca, cb);
          tf2x32(kka, kkb, 0u, 1u, kpa, kpb);
          const int back = __shfl(seqr, i - bsc - 1);
          const uint32_t pm = nb01L[back];
          const int m0 = (int)(pm & 0xffffu), m1 = (int)(pm >> 16);
          const int m2 = (int)nb2L[back];
          const uint32_t e0 = ((visW[(unsigned)m0 >> 5] >> (m0 & 31)) & 1u) ^ 1u;
          const uint32_t e1 = ((visW[(unsigned)m1 >> 5] >> (m1 & 31)) & 1u) ^ 1u;
          const uint32_t e2 = ((visW[(unsigned)m2 >> 5] >> (m2 & 31)) & 1u) ^ 1u;
          const uint32_t bc = e0 + e1 + e2;
          if (bc > 0) {
            uint32_t bhi, blo;
            randbits(kpa, kpb, bhi, blo);
            const uint32_t bcode = pick_code(bhi, blo);
            const uint32_t r3 = bcode & 3u, r2 = (bcode >> 2) & 1u;
            const uint32_t t2v = (bc == 3 ? r3 : (bc == 2 ? r2 : 0)) + 1;
            ta = (e0 == t2v) ? m0 : ((e0 + e1 == t2v) ? m1 : m2);
            found = true;
          } else {
            bsc += 2;
          }
          kka = ca; kkb = cb;
        }
        if (found) {
          to_add = ta;
          const int i_new = i - bsc;
          seqr = (lane >= i_new && lane < i) ? to_add : seqr;  // splat
          bs = bsc; i = i_new;
        } else {
          uint32_t k3a, k3b, rhi, rlo;
          tf2x32(kia, kib, 0u, 3u, k3a, k3b);  // k3
          randbits(k3a, k3b, rhi, rlo);
          to_add = (int)r_generic(rhi, rlo, (uint32_t)N);
          bs = 1;
        }
        // set bit (fresh read; in-order DS within wave)
        if (lane == 0)
          visW[(unsigned)to_add >> 5] |= 1u << (to_add & 31);
        seqr = (lane == i) ? to_add : seqr;
        ++i;
        const uint32_t p = nb01L[to_add];
        n0 = (int)(p & 0xffffu); n1 = (int)(p >> 16); n2 = (int)nb2L[to_add];
        continue;
      }
      // ---- common path: branch-lean ----
      uint32_t code = codeP;
      if (__builtin_expect(idx >= CH, 0)) {   // live tree beyond cached steps
        uint32_t ia, ib, k1a, k1b, hi, lo;
        get_key(idx, ia, ib);
        tf2x32(ia, ib, 0u, 1u, k1a, k1b);
        randbits(k1a, k1b, hi, lo);
        code = pick_code(hi, lo);
      }
      const uint32_t r3 = code & 3u, r2 = (code >> 2) & 1u;
      const uint32_t target = (cnt == 3 ? r3 : (cnt == 2 ? r2 : 0)) + 1;
      sel = (u0 == target) ? 0 : ((u0 + u1 == target) ? 1 : 2);
      to_add = (sel == 0) ? n0 : ((sel == 1) ? n1 : n2);
      // set bit: reuse the word read this iter (includes last iter's write).
      const uint32_t wsel = (sel == 0) ? wv0 : ((sel == 1) ? wv1 : wv2);
      if (lane == 0)
        visW[(unsigned)to_add >> 5] = wsel | (1u << (to_add & 31));
      seqr = (lane == i) ? to_add : seqr;
      bs = 1; ++i;
      if (sel == 0)      { n0 = (int)(pA & 0xffffu); n1 = (int)(pA >> 16); n2 = (int)a2; }
      else if (sel == 1) { n0 = (int)(pB & 0xffffu); n1 = (int)(pB >> 16); n2 = (int)b2; }
      else               { n0 = (int)(pC & 0xffffu); n1 = (int)(pC >> 16); n2 = (int)c2v; }
    }
  } else {
    // ============ global-chase fallback (verified R5/R8 logic) ============
    int hist  = (lane == 0) ? f0 : -1;
    int hist2 = -1;
    int3 row = grow;
    while (i <= L) {
      const int idx = c; ++c;
      const bool deep = (idx >= CH);
      const uint32_t codeP = code_next;
      code_next = (uint32_t)__shfl((int)mycode, (c < CH) ? c : 0);

      const int n0 = row.x, n1 = row.y, n2 = row.z;
      int v0 = __any(hist == n0), v1 = __any(hist == n1), v2 = __any(hist == n2);
      if (deep) {
        v0 |= __any(hist2 == n0); v1 |= __any(hist2 == n1); v2 |= __any(hist2 == n2);
      }
      const int u0 = 1 - v0, u1 = 1 - v1, u2 = 1 - v2;
      const int cnt = u0 + u1 + u2;

      int to_add;
      bool hit = false;
      int bsf = bs;
      if (cnt > 0) {
        uint32_t code = codeP;
        if (deep) {
          uint32_t ia, ib, k1a, k1b, hi, lo;
          get_key(idx, ia, ib);
          tf2x32(ia, ib, 0u, 1u, k1a, k1b);
          randbits(k1a, k1b, hi, lo);
          code = pick_code(hi, lo);
        }
        const int r3 = (int)(code & 3u), r2 = (int)((code >> 2) & 1u);
        const int target = (cnt == 3 ? r3 : (cnt == 2 ? r2 : 0)) + 1;
        to_add = (u0 == target) ? n0 : ((u0 + u1 == target) ? n1 : n2);
      } else {
        uint32_t kia, kib;
        get_key(idx, kia, kib);
        uint32_t kka, kkb;
        tf2x32(kia, kib, 0u, 2u, kka, kkb);
        bool found = false;
        int ta = 0, bsc = bs;
        while (!found && i > bsc) {
          uint32_t ca, cb, kpa, kpb;
          tf2x32(kka, kkb, 0u, 0u, ca, cb);
          tf2x32(kka, kkb, 0u, 1u, kpa, kpb);
          const int back = __shfl(seqr, i - bsc - 1);
          const int3 br = *reinterpret_cast<const int3*>(nb + 3 * (size_t)back);
          int w0m = __any(hist == br.x), w1m = __any(hist == br.y), w2m = __any(hist == br.z);
          if (deep) {
            w0m |= __any(hist2 == br.x); w1m |= __any(hist2 == br.y); w2m |= __any(hist2 == br.z);
          }
          const int e0 = 1 - w0m, e1 = 1 - w1m, e2 = 1 - w2m;
          const int bc = e0 + e1 + e2;
          if (bc > 0) {
            uint32_t bhi, blo;
            randbits(kpa, kpb, bhi, blo);
            const uint32_t bcode = pick_code(bhi, blo);
            const int r3 = (int)(bcode & 3u), r2 = (int)((bcode >> 2) & 1u);
            const int t2v = (bc == 3 ? r3 : (bc == 2 ? r2 : 0)) + 1;
            ta = (e0 == t2v) ? br.x : ((e0 + e1 == t2v) ? br.y : br.z);
            found = true;
          } else {
            bsc += 2;
          }
          kka = ca; kkb = cb;
        }
        if (found) {
          to_add = ta; hit = true; bsf = bsc;
        } else {
          uint32_t k3a, k3b, rhi, rlo;
          tf2x32(kia, kib, 0u, 3u, k3a, k3b);
          randbits(k3a, k3b, rhi, rlo);
          to_add = (int)r_generic(rhi, rlo, (uint32_t)N);
        }
      }

      int i_new, up;
      if (hit) { i_new = i - bsf; bs = bsf; up = i - 1; }
      else     { i_new = i;       bs = 1;   up = i; }
      seqr = (lane >= i_new && lane <= up) ? to_add : seqr;

      const int slot = idx + 1;
      if (slot < CH)          hist  = (lane == slot)      ? to_add : hist;
      else if (slot < 2 * CH) hist2 = (lane == slot - CH) ? to_add : hist2;

      i = i_new + 1;
      row = *reinterpret_cast<const int3*>(nb + 3 * (size_t)to_add);
    }
  }

  // ---- Epilogue: lane t holds seq[t] ------------------------------------
  const float cx = xb[3 * (size_t)f0 + 0];
  const float cy = xb[3 * (size_t)f0 + 1];
  const float cz = xb[3 * (size_t)f0 + 2];
  if (lane < Lp1) {
    const int node = seqr;
    float3 v;
    v.x = xb[3 * (size_t)node + 0] - cx;
    v.y = xb[3 * (size_t)node + 1] - cy;
    v.z = xb[3 * (size_t)node + 2] - cz;
    *reinterpret_cast<float3*>(out + ((size_t)w * Lp1 + lane) * 3) = v;
  }
}

}  // namespace

extern "C" void kernel_launch(void* const* d_in, const int* in_sizes, int n_in,
                              void* d_out, int out_size, void* d_ws, size_t ws_size,
                              hipStream_t stream) {
  const float* xyz     = (const float*)d_in[0];
  const int*   nbrs    = (const int*)d_in[1];
  const int*   centers = (const int*)d_in[2];
  const int*   n_faces = (const int*)d_in[3];
  const int*   seq_len = (const int*)d_in[4];
  float* out = (float*)d_out;

  const int s0 = in_sizes[0];                  // B*N*3
  const int num_walks = in_sizes[2];           // B*G
  const int Lp1 = out_size / (3 * num_walks);  // seq_len+1

  const int blocks = (num_walks + WPB - 1) / WPB;
  walk_kernel<<<blocks, WPB * 64, 0, stream>>>(
      xyz, nbrs, centers, n_faces, seq_len, out, s0, num_walks, Lp1);
}